// Round 6
// baseline (286.781 us; speedup 1.0000x reference)
//
#include <hip/hip_runtime.h>
#include <math.h>

#define S 4096
#define CNUM 128
#define BATCH 4
#define MTOT (BATCH * S)
#define SCLOG2E 0.36067376022224085f   // 0.25 * log2(e): scores in log2 domain
#define EPSLN 1e-5f
#define KSPLIT 8                        // k-range split for fused attn partials
#define QSPLIT 8                        // q-range split for column-sum pass

typedef __attribute__((ext_vector_type(8))) short bf16x8;
typedef __attribute__((ext_vector_type(4))) float f32x4;
typedef __attribute__((ext_vector_type(16))) float f32x16;
typedef __attribute__((ext_vector_type(4))) unsigned int u32x4;

__device__ __forceinline__ float gelu_exact(float x) {
    return 0.5f * x * (1.0f + erff(x * 0.7071067811865476f));
}

__device__ __forceinline__ unsigned short f2b(float f) {
    union { float f; unsigned int u; } v; v.f = f;
    unsigned int r = (v.u + 0x7FFFu + ((v.u >> 16) & 1u)) >> 16;
    return (unsigned short)r;
}
// cheap round-half-up for positive values (2 ops)
__device__ __forceinline__ unsigned short f2b_ru(float f) {
    return (unsigned short)((__float_as_uint(f) + 0x8000u) >> 16);
}
__device__ __forceinline__ float b2f(unsigned short u) {
    return __uint_as_float((unsigned)u << 16);
}

// ---------------- transpose [B,C,S] -> [B,S,C]: t fp32 (residual), xlh bf16 (LN1 out) ----------------
__global__ __launch_bounds__(256) void ln1_transpose(
    const float* __restrict__ x, const float* __restrict__ w, const float* __restrict__ bb,
    unsigned short* __restrict__ xlh, float* __restrict__ t)
{
    __shared__ float tile[128][65];
    __shared__ float mu[64], rs[64];
    const int b = blockIdx.y;
    const int s0 = blockIdx.x * 64;
    const float* xb = x + (size_t)b * CNUM * S;
    for (int i = threadIdx.x; i < 128 * 64; i += 256) {
        int c = i >> 6, sl = i & 63;
        tile[c][sl] = xb[(size_t)c * S + s0 + sl];
    }
    __syncthreads();
    if (threadIdx.x < 64) {
        float sum = 0.f, sq = 0.f;
        for (int c = 0; c < 128; ++c) {
            float v = tile[c][threadIdx.x];
            sum += v; sq += v * v;
        }
        float m = sum * (1.f / 128.f);
        float var = sq * (1.f / 128.f) - m * m;
        mu[threadIdx.x] = m;
        rs[threadIdx.x] = rsqrtf(var + EPSLN);
    }
    __syncthreads();
    for (int i = threadIdx.x; i < 128 * 64; i += 256) {
        int c = i & 127, sl = i >> 7;
        float v = tile[c][sl];
        size_t idx = ((size_t)b * S + s0 + sl) * CNUM + c;
        t[idx] = v;
        xlh[idx] = f2b((v - mu[sl]) * rs[sl] * w[c] + bb[c]);
    }
}

// ---------------- weight convert+transpose fp32[K,N] -> bf16[N,K]; biases packed ----------------
__global__ __launch_bounds__(256) void convw(
    const float* __restrict__ wq, const float* __restrict__ wk, const float* __restrict__ wv,
    const float* __restrict__ wo, const float* __restrict__ w1, const float* __restrict__ w2,
    const float* __restrict__ bq, const float* __restrict__ bk, const float* __restrict__ bv,
    unsigned short* __restrict__ wqkvh, unsigned short* __restrict__ woh,
    unsigned short* __restrict__ w1h, unsigned short* __restrict__ w2h,
    float* __restrict__ bqkv)
{
    int a = blockIdx.y;
    int idx = blockIdx.x * 256 + threadIdx.x;
    if (a == 6) {
        if (idx < 128) bqkv[idx] = bq[idx];
        else if (idx < 256) bqkv[idx] = bk[idx - 128];
        else if (idx < 384) bqkv[idx] = bv[idx - 256];
        return;
    }
    const float* src; unsigned short* dst; int Nsh, Ksz;
    switch (a) {
        case 0: src = wq; dst = wqkvh;          Nsh = 7; Ksz = 128; break;
        case 1: src = wk; dst = wqkvh + 16384;  Nsh = 7; Ksz = 128; break;
        case 2: src = wv; dst = wqkvh + 32768;  Nsh = 7; Ksz = 128; break;
        case 3: src = wo; dst = woh;            Nsh = 7; Ksz = 128; break;
        case 4: src = w1; dst = w1h;            Nsh = 8; Ksz = 128; break;
        default: src = w2; dst = w2h;           Nsh = 7; Ksz = 256; break;
    }
    int total = Ksz << Nsh;
    if (idx >= total) return;
    int k = idx >> Nsh, n = idx & ((1 << Nsh) - 1);
    dst[n * Ksz + k] = f2b(src[idx]);
}

// ---------------- MFMA GEMM: C = A[M,KT](bf16) @ Bt[N,KT]^T(bf16) + bias, epilogues ----------------
// EPI: 3 = fp32 +res -> y[M,N] AND fused LN2 -> bf16 zh[M,N]
//      6 = gelu -> bf16 C[M,N]
//      7 = QKV combined (z=0,1: bf16 [M,128]; z=2: bf16 V^T[b][col][s])
//      8 = gelu + res -> fp32 out[b][col][s] (fused final transpose)
template<int KT, int EPI>
__global__ __launch_bounds__(256) void gemm_mfma(
    const unsigned short* __restrict__ A, const unsigned short* __restrict__ Bt,
    const float* __restrict__ bias, const float* __restrict__ res,
    void* __restrict__ Cv, void* __restrict__ Cv2,
    const float* __restrict__ wln, const float* __restrict__ bln, int N)
{
    constexpr int CH = KT / 8;
    constexpr int CSH = (KT == 128) ? 4 : 5;
    __shared__ unsigned short As[64 * KT];
    __shared__ unsigned short Bs[128 * KT];
    __shared__ float2 lnred[2][64];              // EPI==3 only (1 KB)
    const int bm = blockIdx.y * 64;
    const int bn = blockIdx.x * 128;
    const int z = blockIdx.z;
    const unsigned short* Btz = (EPI == 7) ? Bt + z * 16384 : Bt;
    const float* biasz = (EPI == 7) ? bias + z * 128 : bias;
    const int tid = threadIdx.x;
    const int w = tid >> 6, l = tid & 63;
    const int rw = (w & 1) * 32, cw = (w >> 1) * 64;
    const int lm = l & 15, lq = l >> 4;

    #pragma unroll
    for (int i = 0; i < (64 * CH) / 256; ++i) {
        int cid = i * 256 + tid;
        int r = cid >> CSH, c = cid & (CH - 1);
        int p = (c & ~15) | ((c ^ r) & 15);
        *(ulonglong2*)(As + r * KT + p * 8) =
            *(const ulonglong2*)(A + (size_t)(bm + r) * KT + c * 8);
    }
    #pragma unroll
    for (int i = 0; i < (128 * CH) / 256; ++i) {
        int cid = i * 256 + tid;
        int r = cid >> CSH, c = cid & (CH - 1);
        int p = (c & ~15) | ((c ^ r) & 15);
        *(ulonglong2*)(Bs + r * KT + p * 8) =
            *(const ulonglong2*)(Btz + (size_t)(bn + r) * KT + c * 8);
    }
    __syncthreads();

    f32x4 zero = {0.f, 0.f, 0.f, 0.f};
    f32x4 acc[2][4];
    #pragma unroll
    for (int i = 0; i < 2; ++i)
        #pragma unroll
        for (int j = 0; j < 4; ++j) acc[i][j] = zero;

    #pragma unroll
    for (int ks = 0; ks < KT / 32; ++ks) {
        int c_lin = ks * 4 + lq;
        bf16x8 a[2], bfr[4];
        #pragma unroll
        for (int i = 0; i < 2; ++i) {
            int m = rw + i * 16 + lm;
            int p = (c_lin & ~15) | ((c_lin ^ m) & 15);
            a[i] = *(const bf16x8*)(As + m * KT + p * 8);
        }
        #pragma unroll
        for (int j = 0; j < 4; ++j) {
            int n = cw + j * 16 + lm;
            int p = (c_lin & ~15) | ((c_lin ^ n) & 15);
            bfr[j] = *(const bf16x8*)(Bs + n * KT + p * 8);
        }
        #pragma unroll
        for (int i = 0; i < 2; ++i)
            #pragma unroll
            for (int j = 0; j < 4; ++j)
                acc[i][j] = __builtin_amdgcn_mfma_f32_16x16x32_bf16(a[i], bfr[j], acc[i][j], 0, 0, 0);
    }

    if (EPI == 3) {
        // y = acc + bias + res; then fused LN over the 128-col rows of this 64-row block.
        float vv[2][4][4];
        #pragma unroll
        for (int i = 0; i < 2; ++i) {
            int rowbase = bm + rw + i * 16 + lq * 4;
            #pragma unroll
            for (int j = 0; j < 4; ++j) {
                int col = bn + cw + j * 16 + lm;
                #pragma unroll
                for (int reg = 0; reg < 4; ++reg)
                    vv[i][j][reg] = acc[i][j][reg] + biasz[col] +
                                    res[(size_t)(rowbase + reg) * N + col];
            }
        }
        // per-row partials over this wave's 64-col half: in-thread j-sum, then 16-lane shfl
        #pragma unroll
        for (int i = 0; i < 2; ++i)
            #pragma unroll
            for (int reg = 0; reg < 4; ++reg) {
                float s = 0.f, q = 0.f;
                #pragma unroll
                for (int j = 0; j < 4; ++j) {
                    float xv = vv[i][j][reg];
                    s += xv; q += xv * xv;
                }
                #pragma unroll
                for (int off = 1; off < 16; off <<= 1) {
                    s += __shfl_xor(s, off);
                    q += __shfl_xor(q, off);
                }
                if (lm == 0) {
                    float2 sq2; sq2.x = s; sq2.y = q;
                    lnred[cw >> 6][rw + i * 16 + lq * 4 + reg] = sq2;
                }
            }
        __syncthreads();
        #pragma unroll
        for (int i = 0; i < 2; ++i) {
            #pragma unroll
            for (int reg = 0; reg < 4; ++reg) {
                int lrow = rw + i * 16 + lq * 4 + reg;
                int row = bm + lrow;
                float2 h0 = lnred[0][lrow], h1 = lnred[1][lrow];
                float mean = (h0.x + h1.x) * (1.f / 128.f);
                float var  = (h0.y + h1.y) * (1.f / 128.f) - mean * mean;
                float rs = rsqrtf(var + EPSLN);
                #pragma unroll
                for (int j = 0; j < 4; ++j) {
                    int col = bn + cw + j * 16 + lm;
                    float xv = vv[i][j][reg];
                    ((float*)Cv)[(size_t)row * N + col] = xv;
                    ((unsigned short*)Cv2)[(size_t)row * N + col] =
                        f2b((xv - mean) * rs * wln[col] + bln[col]);
                }
            }
        }
        return;
    }

    #pragma unroll
    for (int i = 0; i < 2; ++i) {
        int rowbase = bm + rw + i * 16 + lq * 4;
        #pragma unroll
        for (int j = 0; j < 4; ++j) {
            int col = bn + cw + j * 16 + lm;
            float v[4];
            #pragma unroll
            for (int reg = 0; reg < 4; ++reg) v[reg] = acc[i][j][reg] + biasz[col];
            if (EPI == 6) {
                #pragma unroll
                for (int reg = 0; reg < 4; ++reg)
                    ((unsigned short*)Cv)[(size_t)(rowbase + reg) * N + col] = f2b(gelu_exact(v[reg]));
            } else if (EPI == 8) {
                int bb = rowbase >> 12, s = rowbase & 4095;
                float4 o;
                o.x = gelu_exact(v[0]) + res[(size_t)(rowbase + 0) * N + col];
                o.y = gelu_exact(v[1]) + res[(size_t)(rowbase + 1) * N + col];
                o.z = gelu_exact(v[2]) + res[(size_t)(rowbase + 2) * N + col];
                o.w = gelu_exact(v[3]) + res[(size_t)(rowbase + 3) * N + col];
                *(float4*)(((float*)Cv) + ((size_t)(bb * 128 + col)) * 4096 + s) = o;
            } else if (EPI == 7) {
                if (z < 2) {
                    unsigned short* dst = ((unsigned short*)Cv) + (size_t)z * MTOT * 128;
                    #pragma unroll
                    for (int reg = 0; reg < 4; ++reg)
                        dst[(size_t)(rowbase + reg) * 128 + col] = f2b(v[reg]);
                } else {
                    // plain V^T[b][col][s]
                    int bb = rowbase >> 12, s = rowbase & 4095;
                    ushort4 o;
                    o.x = f2b(v[0]); o.y = f2b(v[1]); o.z = f2b(v[2]); o.w = f2b(v[3]);
                    *(ushort4*)(((unsigned short*)Cv) + (size_t)2 * MTOT * 128 +
                                ((size_t)(bb * 128 + col)) * 4096 + s) = o;
                }
            }
        }
    }
}

// ---------------- Pass A: column sums L[k] = sum_q f2b_ru(exp2(S[q,k])) — no P store ----------------
// grid (S/128 k-tiles, QSPLIT, BATCH). K-tile staged once; loop over q-tiles of this block's q-range.
__global__ __launch_bounds__(256) void colsum(
    const unsigned short* __restrict__ qh, const unsigned short* __restrict__ kh,
    float* __restrict__ psum_all)
{
    __shared__ unsigned short Qs[128 * 128];
    __shared__ unsigned short Ks[128 * 128];
    __shared__ float csum[2][128];
    const int b = blockIdx.z;
    const unsigned short* Q = qh + (size_t)b * S * 128;
    const unsigned short* Km = kh + (size_t)b * S * 128;
    const int bn = blockIdx.x * 128;
    const int q0 = blockIdx.y * (S / QSPLIT);
    const int tid = threadIdx.x;
    const int w = tid >> 6, l = tid & 63;
    const int wr = (w >> 1) * 64, wc = (w & 1) * 64;
    const int lm = l & 15, lq = l >> 4;

    // stage K tile once (swizzled)
    #pragma unroll
    for (int i = 0; i < 8; ++i) {
        int cid = i * 256 + tid;
        int r = cid >> 4, c = cid & 15;
        int p = c ^ (r & 15);
        *(ulonglong2*)(Ks + r * 128 + p * 8) =
            *(const ulonglong2*)(Km + (size_t)(bn + r) * 128 + c * 8);
    }

    float jsum[4] = {0.f, 0.f, 0.f, 0.f};
    for (int qt = 0; qt < (S / QSPLIT) / 128; ++qt) {
        __syncthreads();   // protect Qs from previous iteration's readers (also covers Ks stage on qt=0)
        #pragma unroll
        for (int i = 0; i < 8; ++i) {
            int cid = i * 256 + tid;
            int r = cid >> 4, c = cid & 15;
            int p = c ^ (r & 15);
            *(ulonglong2*)(Qs + r * 128 + p * 8) =
                *(const ulonglong2*)(Q + (size_t)(q0 + qt * 128 + r) * 128 + c * 8);
        }
        __syncthreads();

        f32x4 zero = {0.f, 0.f, 0.f, 0.f};
        f32x4 acc[4][4];
        #pragma unroll
        for (int i = 0; i < 4; ++i)
            #pragma unroll
            for (int j = 0; j < 4; ++j) acc[i][j] = zero;

        #pragma unroll
        for (int ks = 0; ks < 4; ++ks) {
            bf16x8 a[4], bfr[4];
            #pragma unroll
            for (int i = 0; i < 4; ++i) {
                int m = wr + i * 16 + lm;
                int p = (ks * 4 + lq) ^ (m & 15);
                a[i] = *(const bf16x8*)(Qs + m * 128 + p * 8);
            }
            #pragma unroll
            for (int j = 0; j < 4; ++j) {
                int n = wc + j * 16 + lm;
                int p = (ks * 4 + lq) ^ (n & 15);
                bfr[j] = *(const bf16x8*)(Ks + n * 128 + p * 8);
            }
            #pragma unroll
            for (int i = 0; i < 4; ++i)
                #pragma unroll
                for (int j = 0; j < 4; ++j)
                    acc[i][j] = __builtin_amdgcn_mfma_f32_16x16x32_bf16(a[i], bfr[j], acc[i][j], 0, 0, 0);
        }

        #pragma unroll
        for (int i = 0; i < 4; ++i)
            #pragma unroll
            for (int j = 0; j < 4; ++j)
                #pragma unroll
                for (int reg = 0; reg < 4; ++reg)
                    jsum[j] += b2f(f2b_ru(exp2f(acc[i][j][reg] * SCLOG2E)));
    }

    #pragma unroll
    for (int j = 0; j < 4; ++j) {
        jsum[j] += __shfl_xor(jsum[j], 16);
        jsum[j] += __shfl_xor(jsum[j], 32);
    }
    if (l < 16) {
        #pragma unroll
        for (int j = 0; j < 4; ++j)
            csum[w >> 1][wc + j * 16 + l] = jsum[j];
    }
    __syncthreads();
    if (tid < 128)
        psum_all[((size_t)(blockIdx.y * BATCH + b)) * S + bn + tid] = csum[0][tid] + csum[1][tid];
}

// ---------------- fold 1/L into plain V^T (in place, bf16) ----------------
__global__ __launch_bounds__(256) void vscale(
    unsigned short* __restrict__ Vt_all, const float* __restrict__ psum_all)
{
    const int b = blockIdx.z;
    unsigned short* Vt = Vt_all + (size_t)b * CNUM * S;
    int i = (blockIdx.x * 256 + threadIdx.x) * 4;
    int k = i & (S - 1);
    float4 L = *(const float4*)(psum_all + (size_t)b * S + k);
    #pragma unroll
    for (int t = 1; t < QSPLIT; ++t) {
        float4 Lt = *(const float4*)(psum_all + ((size_t)(t * BATCH + b)) * S + k);
        L.x += Lt.x; L.y += Lt.y; L.z += Lt.z; L.w += Lt.w;
    }
    ushort4 v = *(ushort4*)(Vt + i);
    v.x = f2b(b2f(v.x) / L.x);
    v.y = f2b(b2f(v.y) / L.y);
    v.z = f2b(b2f(v.z) / L.z);
    v.w = f2b(b2f(v.w) / L.w);
    *(ushort4*)(Vt + i) = v;
}

// ---------------- fused attention: out_part = exp2(Q K^T) @ Vhat, k-split ----------------
// grid (KSPLIT, S/128, BATCH), 256 thr. 32x32x16 MFMA throughout. QK^T TRANSPOSED
// (mfma(K,Q) -> S^T): lane holds q = lane&31 and k in consecutive quads — exactly the PV
// A-fragment geometry after 4 v_permlane32_swap_b32 (no P LDS at all, zero conflicts).
// K staged in 8 KB LDS (shared by 4 waves); V read directly from plain V^T (L2-resident)
// as B-fragments via global dwordx4, issued early to hide L2 latency.
__global__ __launch_bounds__(256, 3) void fused_attnv(
    const unsigned short* __restrict__ qh, const unsigned short* __restrict__ kh,
    const unsigned short* __restrict__ Vt_all, unsigned short* __restrict__ parts)
{
    __shared__ unsigned short Ks[32 * 128];      // 8 KB, swizzled slot' = slot ^ (row&15)
    const int b = blockIdx.z;
    const unsigned short* Qm = qh + (size_t)b * S * 128;
    const unsigned short* Km = kh + (size_t)b * S * 128;
    const unsigned short* Vb = Vt_all + (size_t)b * CNUM * S;   // [c][k]
    unsigned short* Pout = parts + (size_t)blockIdx.x * ((size_t)MTOT * CNUM)
                                 + (size_t)b * S * CNUM;
    const int q0 = blockIdx.y * 128;
    const int kb0 = blockIdx.x * (S / KSPLIT);   // 512-k range
    const int tid = threadIdx.x;
    const int w = tid >> 6, l = tid & 63;
    const int lc = l & 31, lh = l >> 5;          // col-lane, half
    const int row0 = q0 + w * 32;

    // Q B-fragments (persistent): aq[d] = Q[row0+lc][d*16 + lh*8 ..+7]
    bf16x8 aq[8];
    #pragma unroll
    for (int d = 0; d < 8; ++d)
        aq[d] = *(const bf16x8*)(Qm + (size_t)(row0 + lc) * 128 + d * 16 + lh * 8);

    f32x16 acco[4];
    #pragma unroll
    for (int cb = 0; cb < 4; ++cb)
        #pragma unroll
        for (int r = 0; r < 16; ++r) acco[cb][r] = 0.f;

    const unsigned short* vrow = Vb + (size_t)lc * S + lh * 8;

    for (int kt = 0; kt < S / KSPLIT / 32; ++kt) {   // 16 tiles of 32 k
        const int kb = kb0 + kt * 32;

        // V chunk0 B-fragments (k = kb + lh*8 ..+7), issued early: L2 latency hides under QK
        bf16x8 v0[4];
        #pragma unroll
        for (int cb = 0; cb < 4; ++cb)
            v0[cb] = *(const bf16x8*)(vrow + (size_t)cb * 32 * S + kb);

        if (kt) __syncthreads();                 // previous tile's Ks readers done
        #pragma unroll
        for (int i2 = 0; i2 < 2; ++i2) {
            int cid = i2 * 256 + tid;
            int r = cid >> 4, c = cid & 15;
            *(ulonglong2*)(Ks + r * 128 + ((c ^ (r & 15)) * 8)) =
                *(const ulonglong2*)(Km + (size_t)(kb + r) * 128 + c * 8);
        }
        __syncthreads();

        // transposed QK^T: S^T[k_local][q]; lane: q = lc, k = (reg&3)+8*(reg>>2)+4*lh
        f32x16 accT;
        #pragma unroll
        for (int r = 0; r < 16; ++r) accT[r] = 0.f;
        #pragma unroll
        for (int d = 0; d < 8; ++d) {
            int slot = d * 2 + lh;
            bf16x8 kf = *(const bf16x8*)(Ks + lc * 128 + ((slot ^ (lc & 15)) * 8));
            accT = __builtin_amdgcn_mfma_f32_32x32x16_bf16(kf, aq[d], accT, 0, 0, 0);
        }

        // V chunk1 fragments (k = kb+16+..) — hide behind exp2
        bf16x8 v1[4];
        #pragma unroll
        for (int cb = 0; cb < 4; ++cb)
            v1[cb] = *(const bf16x8*)(vrow + (size_t)cb * 32 * S + kb + 16);

        // P = exp2 -> bf16 pairs pk[t][p] (t = reg quad: k = t*8 + 4*lh + 2p)
        unsigned int pk[4][2];
        #pragma unroll
        for (int t = 0; t < 4; ++t)
            #pragma unroll
            for (int p = 0; p < 2; ++p) {
                float e0 = exp2f(accT[t * 4 + 2 * p]     * SCLOG2E);
                float e1 = exp2f(accT[t * 4 + 2 * p + 1] * SCLOG2E);
                asm("v_cvt_pk_bf16_f32 %0, %1, %2" : "=v"(pk[t][p]) : "v"(e0), "v"(e1));
            }
        // permlane32_swap: (t0,t1) -> A-frag k 0..15; (t2,t3) -> k 16..31.
        // After swap: pk[t0][p] = word p (own low k + partner's), pk[t1][p] = word 2+p.
        #pragma unroll
        for (int p = 0; p < 2; ++p) {
            asm volatile("v_permlane32_swap_b32 %0, %1" : "+v"(pk[0][p]), "+v"(pk[1][p]));
            asm volatile("v_permlane32_swap_b32 %0, %1" : "+v"(pk[2][p]), "+v"(pk[3][p]));
        }
        u32x4 u0 = {pk[0][0], pk[0][1], pk[1][0], pk[1][1]};
        u32x4 u1 = {pk[2][0], pk[2][1], pk[3][0], pk[3][1]};
        bf16x8 ap0 = __builtin_bit_cast(bf16x8, u0);
        bf16x8 ap1 = __builtin_bit_cast(bf16x8, u1);

        // PV: acco[cb] += P[:, k-chunk] @ Vhat[k-chunk, cb*32..]
        __builtin_amdgcn_s_setprio(1);
        #pragma unroll
        for (int cb = 0; cb < 4; ++cb) {
            acco[cb] = __builtin_amdgcn_mfma_f32_32x32x16_bf16(ap0, v0[cb], acco[cb], 0, 0, 0);
            acco[cb] = __builtin_amdgcn_mfma_f32_32x32x16_bf16(ap1, v1[cb], acco[cb], 0, 0, 0);
        }
        __builtin_amdgcn_s_setprio(0);
    }

    #pragma unroll
    for (int cb = 0; cb < 4; ++cb)
        #pragma unroll
        for (int r = 0; r < 16; ++r) {
            int q = (r & 3) + 8 * (r >> 2) + 4 * lh;
            Pout[(size_t)(row0 + q) * CNUM + cb * 32 + lc] = f2b(acco[cb][r]);
        }
}

// ---------------- reduce KSPLIT bf16 partials -> bf16 attouth ----------------
__global__ __launch_bounds__(256) void reduce8b(
    const ushort4* __restrict__ parts, ushort4* __restrict__ dst)
{
    size_t i = (size_t)blockIdx.x * 256 + threadIdx.x;
    const size_t stride = (size_t)MTOT * CNUM / 4;
    float sx = 0.f, sy = 0.f, sz = 0.f, sw = 0.f;
    #pragma unroll
    for (int p = 0; p < KSPLIT; ++p) {
        ushort4 v = parts[i + p * stride];
        sx += b2f(v.x); sy += b2f(v.y); sz += b2f(v.z); sw += b2f(v.w);
    }
    ushort4 o;
    o.x = f2b(sx); o.y = f2b(sy); o.z = f2b(sz); o.w = f2b(sw);
    dst[i] = o;
}

extern "C" void kernel_launch(void* const* d_in, const int* in_sizes, int n_in,
                              void* d_out, int out_size, void* d_ws, size_t ws_size,
                              hipStream_t stream)
{
    (void)in_sizes; (void)n_in; (void)out_size; (void)ws_size;
    const float* x    = (const float*)d_in[0];
    const float* ln1w = (const float*)d_in[1];
    const float* ln1b = (const float*)d_in[2];
    const float* wq   = (const float*)d_in[3];
    const float* bq   = (const float*)d_in[4];
    const float* wk   = (const float*)d_in[5];
    const float* bk   = (const float*)d_in[6];
    const float* wv   = (const float*)d_in[7];
    const float* bv   = (const float*)d_in[8];
    const float* wo   = (const float*)d_in[9];
    const float* bo   = (const float*)d_in[10];
    const float* ln2w = (const float*)d_in[11];
    const float* ln2b = (const float*)d_in[12];
    const float* w1   = (const float*)d_in[13];
    const float* b1   = (const float*)d_in[14];
    const float* w2   = (const float*)d_in[15];
    const float* b2   = (const float*)d_in[16];
    float* out = (float*)d_out;

    float* ws = (float*)d_ws;
    const size_t NSC = (size_t)MTOT * CNUM;            // 2,097,152
    float* t      = ws;
    float* y      = t + NSC;
    float* psum   = y + NSC;                           // [QSPLIT][B][S]
    unsigned short* parts = (unsigned short*)(psum + (size_t)QSPLIT * BATCH * S); // [KSPLIT][B][S][C]
    unsigned short* xlh = parts + (size_t)KSPLIT * NSC;
    unsigned short* qh  = xlh + NSC;
    unsigned short* kh  = qh + NSC;                    // V^T must follow kh (EPI7 contiguity)
    unsigned short* Vt  = kh + NSC;                    // plain V^T [b][c][k]
    unsigned short* attouth = Vt + NSC;
    unsigned short* zh  = attouth + NSC;
    unsigned short* hh  = zh + NSC;                    // [M,256] bf16
    unsigned short* wqkvh = hh + (size_t)MTOT * 256;
    unsigned short* woh = wqkvh + 3 * 16384;
    unsigned short* w1h = woh + 16384;                 // [256][128]
    unsigned short* w2h = w1h + 32768;                 // [128][256]
    float* bqkv = (float*)(w2h + 32768);               // [384]

    ln1_transpose<<<dim3(S / 64, BATCH), 256, 0, stream>>>(x, ln1w, ln1b, xlh, t);
    convw<<<dim3(128, 7), 256, 0, stream>>>(wq, wk, wv, wo, w1, w2, bq, bk, bv,
                                            wqkvh, woh, w1h, w2h, bqkv);

    // QKV: one launch, z = {q, k, v^T}
    gemm_mfma<128, 7><<<dim3(1, MTOT / 64, 3), 256, 0, stream>>>(
        xlh, wqkvh, bqkv, nullptr, qh, nullptr, nullptr, nullptr, 128);

    colsum<<<dim3(S / 128, QSPLIT, BATCH), 256, 0, stream>>>(qh, kh, psum);
    vscale<<<dim3(CNUM * S / 4 / 256, 1, BATCH), 256, 0, stream>>>(Vt, psum);
    fused_attnv<<<dim3(KSPLIT, S / 128, BATCH), 256, 0, stream>>>(qh, kh, Vt, parts);
    reduce8b<<<NSC / 4 / 256, 256, 0, stream>>>((const ushort4*)parts, (ushort4*)attouth);

    // y = attouth @ wo + bo + t, fused LN2 -> zh
    gemm_mfma<128, 3><<<dim3(1, MTOT / 64), 256, 0, stream>>>(
        attouth, woh, bo, t, y, zh, ln2w, ln2b, 128);
    // hh = gelu(zh @ w1 + b1) -> bf16
    gemm_mfma<128, 6><<<dim3(2, MTOT / 64), 256, 0, stream>>>(
        zh, w1h, b1, nullptr, hh, nullptr, nullptr, nullptr, 256);
    // out[b][c][s] = gelu(hh @ w2 + b2) + y   (fused transpose)
    gemm_mfma<256, 8><<<dim3(1, MTOT / 64), 256, 0, stream>>>(
        hh, w2h, b2, y, out, nullptr, nullptr, nullptr, 128);
}

// Round 7
// 232.657 us; speedup vs baseline: 1.2326x; 1.2326x over previous
//
#include <hip/hip_runtime.h>
#include <math.h>

#define S 4096
#define CNUM 128
#define BATCH 4
#define MTOT (BATCH * S)
#define SCLOG2E 0.36067376022224085f   // 0.25 * log2(e): scores in log2 domain
#define EPSLN 1e-5f
#define KSPLIT 8                        // k-range split for fused attn partials
#define QSPLIT 8                        // q-range split for column-sum pass

typedef __attribute__((ext_vector_type(8))) short bf16x8;
typedef __attribute__((ext_vector_type(4))) float f32x4;
typedef __attribute__((ext_vector_type(16))) float f32x16;
typedef __attribute__((ext_vector_type(4))) unsigned int u32x4;

__device__ __forceinline__ float gelu_exact(float x) {
    return 0.5f * x * (1.0f + erff(x * 0.7071067811865476f));
}

__device__ __forceinline__ unsigned short f2b(float f) {
    union { float f; unsigned int u; } v; v.f = f;
    unsigned int r = (v.u + 0x7FFFu + ((v.u >> 16) & 1u)) >> 16;
    return (unsigned short)r;
}
__device__ __forceinline__ float b2f(unsigned short u) {
    return __uint_as_float((unsigned)u << 16);
}

// async 16B global->LDS (direct DMA, no VGPR round trip)
__device__ __forceinline__ void gl_lds16(const void* g, void* l) {
    __builtin_amdgcn_global_load_lds(
        (__attribute__((address_space(1))) void*)g,
        (__attribute__((address_space(3))) void*)l, 16, 0, 0);
}

// ---------------- transpose [B,C,S] -> [B,S,C]: t fp32 (residual), xlh bf16 (LN1 out) ----------------
__global__ __launch_bounds__(256) void ln1_transpose(
    const float* __restrict__ x, const float* __restrict__ w, const float* __restrict__ bb,
    unsigned short* __restrict__ xlh, float* __restrict__ t)
{
    __shared__ float tile[128][65];
    __shared__ float mu[64], rs[64];
    const int b = blockIdx.y;
    const int s0 = blockIdx.x * 64;
    const float* xb = x + (size_t)b * CNUM * S;
    for (int i = threadIdx.x; i < 128 * 64; i += 256) {
        int c = i >> 6, sl = i & 63;
        tile[c][sl] = xb[(size_t)c * S + s0 + sl];
    }
    __syncthreads();
    if (threadIdx.x < 64) {
        float sum = 0.f, sq = 0.f;
        for (int c = 0; c < 128; ++c) {
            float v = tile[c][threadIdx.x];
            sum += v; sq += v * v;
        }
        float m = sum * (1.f / 128.f);
        float var = sq * (1.f / 128.f) - m * m;
        mu[threadIdx.x] = m;
        rs[threadIdx.x] = rsqrtf(var + EPSLN);
    }
    __syncthreads();
    for (int i = threadIdx.x; i < 128 * 64; i += 256) {
        int c = i & 127, sl = i >> 7;
        float v = tile[c][sl];
        size_t idx = ((size_t)b * S + s0 + sl) * CNUM + c;
        t[idx] = v;
        xlh[idx] = f2b((v - mu[sl]) * rs[sl] * w[c] + bb[c]);
    }
}

// ---------------- weight convert+transpose fp32[K,N] -> bf16[N,K]; biases packed ----------------
__global__ __launch_bounds__(256) void convw(
    const float* __restrict__ wq, const float* __restrict__ wk, const float* __restrict__ wv,
    const float* __restrict__ wo, const float* __restrict__ w1, const float* __restrict__ w2,
    const float* __restrict__ bq, const float* __restrict__ bk, const float* __restrict__ bv,
    unsigned short* __restrict__ wqkvh, unsigned short* __restrict__ woh,
    unsigned short* __restrict__ w1h, unsigned short* __restrict__ w2h,
    float* __restrict__ bqkv)
{
    int a = blockIdx.y;
    int idx = blockIdx.x * 256 + threadIdx.x;
    if (a == 6) {
        if (idx < 128) bqkv[idx] = bq[idx];
        else if (idx < 256) bqkv[idx] = bk[idx - 128];
        else if (idx < 384) bqkv[idx] = bv[idx - 256];
        return;
    }
    const float* src; unsigned short* dst; int Nsh, Ksz;
    switch (a) {
        case 0: src = wq; dst = wqkvh;          Nsh = 7; Ksz = 128; break;
        case 1: src = wk; dst = wqkvh + 16384;  Nsh = 7; Ksz = 128; break;
        case 2: src = wv; dst = wqkvh + 32768;  Nsh = 7; Ksz = 128; break;
        case 3: src = wo; dst = woh;            Nsh = 7; Ksz = 128; break;
        case 4: src = w1; dst = w1h;            Nsh = 8; Ksz = 128; break;
        default: src = w2; dst = w2h;           Nsh = 7; Ksz = 256; break;
    }
    int total = Ksz << Nsh;
    if (idx >= total) return;
    int k = idx >> Nsh, n = idx & ((1 << Nsh) - 1);
    dst[n * Ksz + k] = f2b(src[idx]);
}

// ---------------- MFMA GEMM: C = A[M,KT](bf16) @ Bt[N,KT]^T(bf16) + bias, epilogues ----------------
// EPI: 3 = A is KSPLIT part-slices summed during staging (f2b(sum), bit-identical to reduce8b);
//          fp32 +res -> y[M,N] AND fused LN2 -> bf16 zh[M,N]
//      6 = gelu -> bf16 C[M,N]
//      7 = QKV combined (z=0,1: bf16 [M,128]; z=2: bf16 V written in pre-swizzled
//          per-64k-chunk LDS-image layout)
//      8 = gelu + res -> fp32 out[b][col][s] (fused final transpose)
template<int KT, int EPI>
__global__ __launch_bounds__(256) void gemm_mfma(
    const unsigned short* __restrict__ A, const unsigned short* __restrict__ Bt,
    const float* __restrict__ bias, const float* __restrict__ res,
    void* __restrict__ Cv, void* __restrict__ Cv2,
    const float* __restrict__ wln, const float* __restrict__ bln, int N)
{
    constexpr int CH = KT / 8;
    constexpr int CSH = (KT == 128) ? 4 : 5;
    __shared__ unsigned short As[64 * KT];
    __shared__ unsigned short Bs[128 * KT];
    __shared__ float2 lnred[2][64];              // EPI==3 only (1 KB)
    const int bm = blockIdx.y * 64;
    const int bn = blockIdx.x * 128;
    const int z = blockIdx.z;
    const unsigned short* Btz = (EPI == 7) ? Bt + z * 16384 : Bt;
    const float* biasz = (EPI == 7) ? bias + z * 128 : bias;
    const int tid = threadIdx.x;
    const int w = tid >> 6, l = tid & 63;
    const int rw = (w & 1) * 32, cw = (w >> 1) * 64;
    const int lm = l & 15, lq = l >> 4;

    if (EPI == 3) {
        // A-stage fused with the KSPLIT-partial reduction (replaces reduce8b kernel)
        #pragma unroll
        for (int i = 0; i < (64 * CH) / 256; ++i) {
            int cid = i * 256 + tid;
            int r = cid >> CSH, c = cid & (CH - 1);
            int p = (c & ~15) | ((c ^ r) & 15);
            float s8[8];
            #pragma unroll
            for (int j = 0; j < 8; ++j) s8[j] = 0.f;
            #pragma unroll
            for (int pp = 0; pp < KSPLIT; ++pp) {
                const unsigned short* src = A + (size_t)pp * ((size_t)MTOT * CNUM)
                                              + (size_t)(bm + r) * KT + c * 8;
                ushort4 u0 = *(const ushort4*)(src);
                ushort4 u1 = *(const ushort4*)(src + 4);
                s8[0] += b2f(u0.x); s8[1] += b2f(u0.y); s8[2] += b2f(u0.z); s8[3] += b2f(u0.w);
                s8[4] += b2f(u1.x); s8[5] += b2f(u1.y); s8[6] += b2f(u1.z); s8[7] += b2f(u1.w);
            }
            ushort4 o0, o1;
            o0.x = f2b(s8[0]); o0.y = f2b(s8[1]); o0.z = f2b(s8[2]); o0.w = f2b(s8[3]);
            o1.x = f2b(s8[4]); o1.y = f2b(s8[5]); o1.z = f2b(s8[6]); o1.w = f2b(s8[7]);
            *(ushort4*)(As + r * KT + p * 8) = o0;
            *(ushort4*)(As + r * KT + p * 8 + 4) = o1;
        }
    } else {
        #pragma unroll
        for (int i = 0; i < (64 * CH) / 256; ++i) {
            int cid = i * 256 + tid;
            int r = cid >> CSH, c = cid & (CH - 1);
            int p = (c & ~15) | ((c ^ r) & 15);
            *(ulonglong2*)(As + r * KT + p * 8) =
                *(const ulonglong2*)(A + (size_t)(bm + r) * KT + c * 8);
        }
    }
    #pragma unroll
    for (int i = 0; i < (128 * CH) / 256; ++i) {
        int cid = i * 256 + tid;
        int r = cid >> CSH, c = cid & (CH - 1);
        int p = (c & ~15) | ((c ^ r) & 15);
        *(ulonglong2*)(Bs + r * KT + p * 8) =
            *(const ulonglong2*)(Btz + (size_t)(bn + r) * KT + c * 8);
    }
    __syncthreads();

    f32x4 zero = {0.f, 0.f, 0.f, 0.f};
    f32x4 acc[2][4];
    #pragma unroll
    for (int i = 0; i < 2; ++i)
        #pragma unroll
        for (int j = 0; j < 4; ++j) acc[i][j] = zero;

    #pragma unroll
    for (int ks = 0; ks < KT / 32; ++ks) {
        int c_lin = ks * 4 + lq;
        bf16x8 a[2], bfr[4];
        #pragma unroll
        for (int i = 0; i < 2; ++i) {
            int m = rw + i * 16 + lm;
            int p = (c_lin & ~15) | ((c_lin ^ m) & 15);
            a[i] = *(const bf16x8*)(As + m * KT + p * 8);
        }
        #pragma unroll
        for (int j = 0; j < 4; ++j) {
            int n = cw + j * 16 + lm;
            int p = (c_lin & ~15) | ((c_lin ^ n) & 15);
            bfr[j] = *(const bf16x8*)(Bs + n * KT + p * 8);
        }
        #pragma unroll
        for (int i = 0; i < 2; ++i)
            #pragma unroll
            for (int j = 0; j < 4; ++j)
                acc[i][j] = __builtin_amdgcn_mfma_f32_16x16x32_bf16(a[i], bfr[j], acc[i][j], 0, 0, 0);
    }

    if (EPI == 3) {
        // y = acc + bias + res; then fused LN over the 128-col rows of this 64-row block.
        float vv[2][4][4];
        #pragma unroll
        for (int i = 0; i < 2; ++i) {
            int rowbase = bm + rw + i * 16 + lq * 4;
            #pragma unroll
            for (int j = 0; j < 4; ++j) {
                int col = bn + cw + j * 16 + lm;
                #pragma unroll
                for (int reg = 0; reg < 4; ++reg)
                    vv[i][j][reg] = acc[i][j][reg] + biasz[col] +
                                    res[(size_t)(rowbase + reg) * N + col];
            }
        }
        #pragma unroll
        for (int i = 0; i < 2; ++i)
            #pragma unroll
            for (int reg = 0; reg < 4; ++reg) {
                float s = 0.f, q = 0.f;
                #pragma unroll
                for (int j = 0; j < 4; ++j) {
                    float xv = vv[i][j][reg];
                    s += xv; q += xv * xv;
                }
                #pragma unroll
                for (int off = 1; off < 16; off <<= 1) {
                    s += __shfl_xor(s, off);
                    q += __shfl_xor(q, off);
                }
                if (lm == 0) {
                    float2 sq2; sq2.x = s; sq2.y = q;
                    lnred[cw >> 6][rw + i * 16 + lq * 4 + reg] = sq2;
                }
            }
        __syncthreads();
        #pragma unroll
        for (int i = 0; i < 2; ++i) {
            #pragma unroll
            for (int reg = 0; reg < 4; ++reg) {
                int lrow = rw + i * 16 + lq * 4 + reg;
                int row = bm + lrow;
                float2 h0 = lnred[0][lrow], h1 = lnred[1][lrow];
                float mean = (h0.x + h1.x) * (1.f / 128.f);
                float var  = (h0.y + h1.y) * (1.f / 128.f) - mean * mean;
                float rs = rsqrtf(var + EPSLN);
                #pragma unroll
                for (int j = 0; j < 4; ++j) {
                    int col = bn + cw + j * 16 + lm;
                    float xv = vv[i][j][reg];
                    ((float*)Cv)[(size_t)row * N + col] = xv;
                    ((unsigned short*)Cv2)[(size_t)row * N + col] =
                        f2b((xv - mean) * rs * wln[col] + bln[col]);
                }
            }
        }
        return;
    }

    #pragma unroll
    for (int i = 0; i < 2; ++i) {
        int rowbase = bm + rw + i * 16 + lq * 4;
        #pragma unroll
        for (int j = 0; j < 4; ++j) {
            int col = bn + cw + j * 16 + lm;
            float v[4];
            #pragma unroll
            for (int reg = 0; reg < 4; ++reg) v[reg] = acc[i][j][reg] + biasz[col];
            if (EPI == 6) {
                #pragma unroll
                for (int reg = 0; reg < 4; ++reg)
                    ((unsigned short*)Cv)[(size_t)(rowbase + reg) * N + col] = f2b(gelu_exact(v[reg]));
            } else if (EPI == 8) {
                int bb = rowbase >> 12, s = rowbase & 4095;
                float4 o;
                o.x = gelu_exact(v[0]) + res[(size_t)(rowbase + 0) * N + col];
                o.y = gelu_exact(v[1]) + res[(size_t)(rowbase + 1) * N + col];
                o.z = gelu_exact(v[2]) + res[(size_t)(rowbase + 2) * N + col];
                o.w = gelu_exact(v[3]) + res[(size_t)(rowbase + 3) * N + col];
                *(float4*)(((float*)Cv) + ((size_t)(bb * 128 + col)) * 4096 + s) = o;
            } else if (EPI == 7) {
                if (z < 2) {
                    unsigned short* dst = ((unsigned short*)Cv) + (size_t)z * MTOT * 128;
                    #pragma unroll
                    for (int reg = 0; reg < 4; ++reg)
                        dst[(size_t)(rowbase + reg) * 128 + col] = f2b(v[reg]);
                } else {
                    // V pre-swizzled image: chunk = (bb*64 + s/64), 8192 elems each.
                    // offset = c*64 + ((g ^ (c&7))*8) + (k&7), g = (k_local>>3)&7.
                    int bb = rowbase >> 12, s = rowbase & 4095;
                    int kc = s >> 6, g = (s >> 3) & 7;
                    ushort4 o;
                    o.x = f2b(v[0]); o.y = f2b(v[1]); o.z = f2b(v[2]); o.w = f2b(v[3]);
                    *(ushort4*)(((unsigned short*)Cv) + (size_t)2 * MTOT * 128 +
                                (((size_t)bb * 64 + kc) << 13) +
                                col * 64 + ((g ^ (col & 7)) << 3) + (s & 7)) = o;
                }
            }
        }
    }
}

// ---------------- Pass A: column sums L[k] = sum_q exp2(S[q,k]) — no P store ----------------
// grid (S/128 k-tiles, QSPLIT, BATCH). K-tile staged once; loop over q-tiles of this block's q-range.
__global__ __launch_bounds__(256) void colsum(
    const unsigned short* __restrict__ qh, const unsigned short* __restrict__ kh,
    float* __restrict__ psum_all)
{
    __shared__ unsigned short Qs[128 * 128];
    __shared__ unsigned short Ks[128 * 128];
    __shared__ float csum[2][128];
    const int b = blockIdx.z;
    const unsigned short* Q = qh + (size_t)b * S * 128;
    const unsigned short* Km = kh + (size_t)b * S * 128;
    const int bn = blockIdx.x * 128;
    const int q0 = blockIdx.y * (S / QSPLIT);
    const int tid = threadIdx.x;
    const int w = tid >> 6, l = tid & 63;
    const int wr = (w >> 1) * 64, wc = (w & 1) * 64;
    const int lm = l & 15, lq = l >> 4;

    #pragma unroll
    for (int i = 0; i < 8; ++i) {
        int cid = i * 256 + tid;
        int r = cid >> 4, c = cid & 15;
        int p = c ^ (r & 15);
        *(ulonglong2*)(Ks + r * 128 + p * 8) =
            *(const ulonglong2*)(Km + (size_t)(bn + r) * 128 + c * 8);
    }

    float jsum[4] = {0.f, 0.f, 0.f, 0.f};
    for (int qt = 0; qt < (S / QSPLIT) / 128; ++qt) {
        __syncthreads();
        #pragma unroll
        for (int i = 0; i < 8; ++i) {
            int cid = i * 256 + tid;
            int r = cid >> 4, c = cid & 15;
            int p = c ^ (r & 15);
            *(ulonglong2*)(Qs + r * 128 + p * 8) =
                *(const ulonglong2*)(Q + (size_t)(q0 + qt * 128 + r) * 128 + c * 8);
        }
        __syncthreads();

        f32x4 zero = {0.f, 0.f, 0.f, 0.f};
        f32x4 acc[4][4];
        #pragma unroll
        for (int i = 0; i < 4; ++i)
            #pragma unroll
            for (int j = 0; j < 4; ++j) acc[i][j] = zero;

        #pragma unroll
        for (int ks = 0; ks < 4; ++ks) {
            bf16x8 a[4], bfr[4];
            #pragma unroll
            for (int i = 0; i < 4; ++i) {
                int m = wr + i * 16 + lm;
                int p = (ks * 4 + lq) ^ (m & 15);
                a[i] = *(const bf16x8*)(Qs + m * 128 + p * 8);
            }
            #pragma unroll
            for (int j = 0; j < 4; ++j) {
                int n = wc + j * 16 + lm;
                int p = (ks * 4 + lq) ^ (n & 15);
                bfr[j] = *(const bf16x8*)(Ks + n * 128 + p * 8);
            }
            #pragma unroll
            for (int i = 0; i < 4; ++i)
                #pragma unroll
                for (int j = 0; j < 4; ++j)
                    acc[i][j] = __builtin_amdgcn_mfma_f32_16x16x32_bf16(a[i], bfr[j], acc[i][j], 0, 0, 0);
        }

        #pragma unroll
        for (int i = 0; i < 4; ++i)
            #pragma unroll
            for (int j = 0; j < 4; ++j)
                #pragma unroll
                for (int reg = 0; reg < 4; ++reg)
                    jsum[j] += exp2f(acc[i][j][reg] * SCLOG2E);
    }

    #pragma unroll
    for (int j = 0; j < 4; ++j) {
        jsum[j] += __shfl_xor(jsum[j], 16);
        jsum[j] += __shfl_xor(jsum[j], 32);
    }
    if (l < 16) {
        #pragma unroll
        for (int j = 0; j < 4; ++j)
            csum[w >> 1][wc + j * 16 + l] = jsum[j];
    }
    __syncthreads();
    if (tid < 128)
        psum_all[((size_t)(blockIdx.y * BATCH + b)) * S + bn + tid] = csum[0][tid] + csum[1][tid];
}

// ---------------- fold 1/L into V image (in place, bf16); k recovered from swizzled offset ----------------
__global__ __launch_bounds__(256) void vscale(
    unsigned short* __restrict__ Vimg_all, const float* __restrict__ psum_all)
{
    const int b = blockIdx.z;
    unsigned short* Vimg = Vimg_all + (size_t)b * CNUM * S;
    int i = (blockIdx.x * 256 + threadIdx.x) * 4;   // elem offset within batch image
    int kc = i >> 13;
    int off = i & 8191;
    int c = off >> 6;
    int p = (off >> 3) & 7;
    int g = p ^ (c & 7);
    int k = kc * 64 + g * 8 + (off & 7);
    float4 L = *(const float4*)(psum_all + (size_t)b * S + k);
    #pragma unroll
    for (int t = 1; t < QSPLIT; ++t) {
        float4 Lt = *(const float4*)(psum_all + ((size_t)(t * BATCH + b)) * S + k);
        L.x += Lt.x; L.y += Lt.y; L.z += Lt.z; L.w += Lt.w;
    }
    ushort4 v = *(ushort4*)(Vimg + i);
    v.x = f2b(b2f(v.x) / L.x);
    v.y = f2b(b2f(v.y) / L.y);
    v.z = f2b(b2f(v.z) / L.z);
    v.w = f2b(b2f(v.w) / L.w);
    *(ushort4*)(Vimg + i) = v;
}

// ---------------- fused attention: out_part = exp2(Q K^T) @ Vhat, k-split ----------------
// grid (KSPLIT, S/128, BATCH), 256 thr. 32x32x16 MFMA. QK^T TRANSPOSED (mfma(K,Q) -> S^T):
// lane holds q = lane&31, k in consecutive quads -> P redistributes to the PV A-fragment with
// 4 v_permlane32_swap_b32 (no P LDS, zero conflicts — round-6-verified). V via pre-swizzled
// image chunks DMA'd by global_load_lds into 16 KB LDS (round-5-verified path): coalesced,
// shared across waves, conflict-free swizzled ds_read. K in 8 KB LDS. Total LDS 24 KB.
__global__ __launch_bounds__(256, 2) void fused_attnv(
    const unsigned short* __restrict__ qh, const unsigned short* __restrict__ kh,
    const unsigned short* __restrict__ Vimg_all, unsigned short* __restrict__ parts)
{
    __shared__ unsigned short Ks[32 * 128];      // 8 KB, swizzled slot' = slot ^ (row&15)
    __shared__ unsigned short Vls[128 * 64];     // 16 KB image chunk (linear DMA)
    const int b = blockIdx.z;
    const unsigned short* Qm = qh + (size_t)b * S * 128;
    const unsigned short* Km = kh + (size_t)b * S * 128;
    const unsigned short* Vimg = Vimg_all + (((size_t)b * 64) << 13);
    unsigned short* Pout = parts + (size_t)blockIdx.x * ((size_t)MTOT * CNUM)
                                 + (size_t)b * S * CNUM;
    const int q0 = blockIdx.y * 128;
    const int kb0 = blockIdx.x * (S / KSPLIT);       // 512-k range
    const int kc0 = blockIdx.x * (S / KSPLIT / 64);  // first 64-k V chunk
    const int tid = threadIdx.x;
    const int w = tid >> 6, l = tid & 63;
    const int lc = l & 31, lh = l >> 5;              // col-lane, half
    const int row0 = q0 + w * 32;

    // Q B-fragments (persistent): aq[d] = Q[row0+lc][d*16 + lh*8 ..+7]
    bf16x8 aq[8];
    #pragma unroll
    for (int d = 0; d < 8; ++d)
        aq[d] = *(const bf16x8*)(Qm + (size_t)(row0 + lc) * 128 + d * 16 + lh * 8);

    f32x16 acco[4];
    #pragma unroll
    for (int cb = 0; cb < 4; ++cb)
        #pragma unroll
        for (int r = 0; r < 16; ++r) acco[cb][r] = 0.f;

    for (int kt = 0; kt < S / KSPLIT / 32; ++kt) {   // 16 tiles of 32 k
        const int kb = kb0 + kt * 32;
        if (kt) __syncthreads();                     // previous tile's Ks/Vls readers done
        // stage K tile [32][128] with read swizzle
        #pragma unroll
        for (int i2 = 0; i2 < 2; ++i2) {
            int cid = i2 * 256 + tid;
            int r = cid >> 4, c = cid & 15;
            *(ulonglong2*)(Ks + r * 128 + ((c ^ (r & 15)) * 8)) =
                *(const ulonglong2*)(Km + (size_t)(kb + r) * 128 + c * 8);
        }
        // stage V 64-chunk every other tile (pre-swizzled image, linear DMA)
        if ((kt & 1) == 0) {
            const unsigned short* src = Vimg + ((size_t)(kc0 + (kt >> 1)) << 13) + tid * 8;
            #pragma unroll
            for (int i2 = 0; i2 < 4; ++i2)
                gl_lds16(src + i2 * 2048, &Vls[(i2 * 256 + tid) * 8]);
        }
        __syncthreads();

        // transposed QK^T: S^T; lane: q = lc, k = (reg&3)+8*(reg>>2)+4*lh
        f32x16 accT;
        #pragma unroll
        for (int r = 0; r < 16; ++r) accT[r] = 0.f;
        #pragma unroll
        for (int d = 0; d < 8; ++d) {
            int slot = d * 2 + lh;
            bf16x8 kf = *(const bf16x8*)(Ks + lc * 128 + ((slot ^ (lc & 15)) * 8));
            accT = __builtin_amdgcn_mfma_f32_32x32x16_bf16(kf, aq[d], accT, 0, 0, 0);
        }

        // P = exp2 -> bf16 pairs pk[t][p] (t = reg quad: k = t*8 + 4*lh + 2p)
        unsigned int pk[4][2];
        #pragma unroll
        for (int t = 0; t < 4; ++t)
            #pragma unroll
            for (int p = 0; p < 2; ++p) {
                float e0 = exp2f(accT[t * 4 + 2 * p]     * SCLOG2E);
                float e1 = exp2f(accT[t * 4 + 2 * p + 1] * SCLOG2E);
                asm("v_cvt_pk_bf16_f32 %0, %1, %2" : "=v"(pk[t][p]) : "v"(e0), "v"(e1));
            }
        // permlane32_swap: (t0,t1) -> A-frag k 0..15; (t2,t3) -> k 16..31 (round-6-verified)
        #pragma unroll
        for (int p = 0; p < 2; ++p) {
            asm volatile("v_permlane32_swap_b32 %0, %1" : "+v"(pk[0][p]), "+v"(pk[1][p]));
            asm volatile("v_permlane32_swap_b32 %0, %1" : "+v"(pk[2][p]), "+v"(pk[3][p]));
        }
        u32x4 u0 = {pk[0][0], pk[0][1], pk[1][0], pk[1][1]};
        u32x4 u1 = {pk[2][0], pk[2][1], pk[3][0], pk[3][1]};
        bf16x8 ap0 = __builtin_bit_cast(bf16x8, u0);
        bf16x8 ap1 = __builtin_bit_cast(bf16x8, u1);

        // PV B-frags from image chunk: g = (kt&1)*4 + khalf*2 + lh
        const int g0 = (kt & 1) * 4 + lh;
        const int g1 = g0 + 2;
        __builtin_amdgcn_s_setprio(1);
        #pragma unroll
        for (int cb = 0; cb < 4; ++cb) {
            int c = cb * 32 + lc;
            bf16x8 v0 = *(const bf16x8*)(Vls + c * 64 + ((g0 ^ (c & 7)) << 3));
            bf16x8 v1 = *(const bf16x8*)(Vls + c * 64 + ((g1 ^ (c & 7)) << 3));
            acco[cb] = __builtin_amdgcn_mfma_f32_32x32x16_bf16(ap0, v0, acco[cb], 0, 0, 0);
            acco[cb] = __builtin_amdgcn_mfma_f32_32x32x16_bf16(ap1, v1, acco[cb], 0, 0, 0);
        }
        __builtin_amdgcn_s_setprio(0);
    }

    #pragma unroll
    for (int cb = 0; cb < 4; ++cb)
        #pragma unroll
        for (int r = 0; r < 16; ++r) {
            int q = (r & 3) + 8 * (r >> 2) + 4 * lh;
            Pout[(size_t)(row0 + q) * CNUM + cb * 32 + lc] = f2b(acco[cb][r]);
        }
}

extern "C" void kernel_launch(void* const* d_in, const int* in_sizes, int n_in,
                              void* d_out, int out_size, void* d_ws, size_t ws_size,
                              hipStream_t stream)
{
    (void)in_sizes; (void)n_in; (void)out_size; (void)ws_size;
    const float* x    = (const float*)d_in[0];
    const float* ln1w = (const float*)d_in[1];
    const float* ln1b = (const float*)d_in[2];
    const float* wq   = (const float*)d_in[3];
    const float* bq   = (const float*)d_in[4];
    const float* wk   = (const float*)d_in[5];
    const float* bk   = (const float*)d_in[6];
    const float* wv   = (const float*)d_in[7];
    const float* bv   = (const float*)d_in[8];
    const float* wo   = (const float*)d_in[9];
    const float* bo   = (const float*)d_in[10];
    const float* ln2w = (const float*)d_in[11];
    const float* ln2b = (const float*)d_in[12];
    const float* w1   = (const float*)d_in[13];
    const float* b1   = (const float*)d_in[14];
    const float* w2   = (const float*)d_in[15];
    const float* b2   = (const float*)d_in[16];
    float* out = (float*)d_out;

    float* ws = (float*)d_ws;
    const size_t NSC = (size_t)MTOT * CNUM;            // 2,097,152
    float* t      = ws;
    float* y      = t + NSC;
    float* psum   = y + NSC;                           // [QSPLIT][B][S]
    unsigned short* parts = (unsigned short*)(psum + (size_t)QSPLIT * BATCH * S); // [KSPLIT][B][S][C]
    unsigned short* xlh = parts + (size_t)KSPLIT * NSC;
    unsigned short* qh  = xlh + NSC;
    unsigned short* kh  = qh + NSC;                    // V image must follow kh (EPI7 contiguity)
    unsigned short* Vt  = kh + NSC;                    // pre-swizzled V image
    unsigned short* zh  = Vt + NSC;
    unsigned short* hh  = zh + NSC;                    // [M,256] bf16
    unsigned short* wqkvh = hh + (size_t)MTOT * 256;
    unsigned short* woh = wqkvh + 3 * 16384;
    unsigned short* w1h = woh + 16384;                 // [256][128]
    unsigned short* w2h = w1h + 32768;                 // [128][256]
    float* bqkv = (float*)(w2h + 32768);               // [384]

    ln1_transpose<<<dim3(S / 64, BATCH), 256, 0, stream>>>(x, ln1w, ln1b, xlh, t);
    convw<<<dim3(128, 7), 256, 0, stream>>>(wq, wk, wv, wo, w1, w2, bq, bk, bv,
                                            wqkvh, woh, w1h, w2h, bqkv);

    // QKV: one launch, z = {q, k, v(image)}
    gemm_mfma<128, 7><<<dim3(1, MTOT / 64, 3), 256, 0, stream>>>(
        xlh, wqkvh, bqkv, nullptr, qh, nullptr, nullptr, nullptr, 128);

    colsum<<<dim3(S / 128, QSPLIT, BATCH), 256, 0, stream>>>(qh, kh, psum);
    vscale<<<dim3(CNUM * S / 4 / 256, 1, BATCH), 256, 0, stream>>>(Vt, psum);
    fused_attnv<<<dim3(KSPLIT, S / 128, BATCH), 256, 0, stream>>>(qh, kh, Vt, parts);

    // y = sum(parts) @ wo + bo + t (A-stage fused reduction), fused LN2 -> zh
    gemm_mfma<128, 3><<<dim3(1, MTOT / 64), 256, 0, stream>>>(
        parts, woh, bo, t, y, zh, ln2w, ln2b, 128);
    // hh = gelu(zh @ w1 + b1) -> bf16
    gemm_mfma<128, 6><<<dim3(2, MTOT / 64), 256, 0, stream>>>(
        zh, w1h, b1, nullptr, hh, nullptr, nullptr, nullptr, 256);
    // out[b][c][s] = gelu(hh @ w2 + b2) + y   (fused transpose)
    gemm_mfma<256, 8><<<dim3(1, MTOT / 64), 256, 0, stream>>>(
        hh, w2h, b2, y, out, nullptr, nullptr, nullptr, 128);
}